// Round 1
// baseline (1108.336 us; speedup 1.0000x reference)
//
#include <hip/hip_runtime.h>
#include <math.h>

// Problem dims (fixed by reference)
#define Bsz 64
#define Ssz 512
#define Hsz 400
#define Dsz 400
#define Vsz 32000
#define Lsz 16
#define H3  1200   // 3*H

// Workspace layout (float offsets)
// xq / hq buffers store transposed activations in [k4][b][4] float4 tiles:
//   value X[b][k] lives at  (k>>2)*256 + b*4 + (k&3)
#define XQ_OFF   0                       // 25600 floats
#define HQA_OFF  25600                   // 25600
#define HQB_OFF  51200                   // 25600
#define GB_OFF   76800                   // 2 splits * 2 gates * 1200 j * 64 b = 307200
#define SC_OFF   384000                  // 64*512 = 32768
// total 416768 floats = ~1.67 MB of ws

__device__ __forceinline__ int qaddr(int d, int b) {
    return (d >> 2) * (Bsz * 4) + b * 4 + (d & 3);
}

// ---------------------------------------------------------------------------
// Init: h0 = encoded_hidden[0] (transposed tile), x0 = slot_emb[slot] broadcast
// ---------------------------------------------------------------------------
__global__ __launch_bounds__(256) void k_init(const float* __restrict__ enc_hidden,
                                              const float* __restrict__ slot_emb,
                                              const int* __restrict__ slot_p,
                                              float* __restrict__ ws) {
    int i = blockIdx.x * 256 + threadIdx.x;
    if (i >= Bsz * Hsz) return;
    int b = i / Hsz, d = i % Hsz;
    int slot = slot_p[0];
    int qa = qaddr(d, b);
    ws[HQA_OFF + qa] = enc_hidden[b * Hsz + d];
    ws[XQ_OFF + qa]  = slot_emb[slot * Dsz + d];
}

// ---------------------------------------------------------------------------
// Gates: gi = x @ W_ih^T, gh = h @ W_hh^T  (no bias; bias added in finalize)
// lanes = batch (64), each wave owns 8 consecutive j rows of one gate matrix,
// k split in 2 chunks of 200.  W reads are wave-uniform -> scalar loads.
// gbuf[((split*2+gate)*1200 + j)*64 + b]
// ---------------------------------------------------------------------------
__global__ __launch_bounds__(256) void k_gates(const float* __restrict__ W_ih,
                                               const float* __restrict__ W_hh,
                                               const float* __restrict__ xq,
                                               const float* __restrict__ hq_cur,
                                               float* __restrict__ gbuf) {
    int lane = threadIdx.x & 63;
    int wid  = __builtin_amdgcn_readfirstlane(threadIdx.x >> 6);
    int gw   = blockIdx.x * 4 + wid;          // 0..599
    int split = gw / 300;
    int rem   = gw % 300;
    int gate  = rem / 150;                    // 0 = ih, 1 = hh
    int j0    = (rem % 150) * 8;
    int k4beg = split * 50;                   // k chunk of 200 floats = 50 float4

    const float*  W   = gate ? W_hh : W_ih;   // both [1200,400] row-major
    const float4* in4 = (const float4*)(gate ? hq_cur : xq);

    float acc[8] = {0.f,0.f,0.f,0.f,0.f,0.f,0.f,0.f};
    for (int k4 = k4beg; k4 < k4beg + 50; ++k4) {
        float4 iv = in4[k4 * 64 + lane];      // x[b][4k4..4k4+3]
        #pragma unroll
        for (int jj = 0; jj < 8; ++jj) {
            const float4 w4 = *(const float4*)(W + (j0 + jj) * Hsz + 4 * k4);
            acc[jj] = fmaf(w4.x, iv.x, acc[jj]);
            acc[jj] = fmaf(w4.y, iv.y, acc[jj]);
            acc[jj] = fmaf(w4.z, iv.z, acc[jj]);
            acc[jj] = fmaf(w4.w, iv.w, acc[jj]);
        }
    }
    float* gout = gbuf + ((size_t)((split * 2 + gate) * H3 + j0)) * 64 + lane;
    #pragma unroll
    for (int jj = 0; jj < 8; ++jj) gout[jj * 64] = acc[jj];
}

// ---------------------------------------------------------------------------
// Score: finalize GRU (duplicated per s-chunk block; only chunk 0 persists h),
// then scores[b][s] = dot(h_new[b], enc_out[b][s]) for 128 s per block.
// grid = 256 blocks: b = blk>>2, schunk = blk&3
// ---------------------------------------------------------------------------
__global__ __launch_bounds__(256) void k_score(const float* __restrict__ gbuf,
                                               const float* __restrict__ b_ih,
                                               const float* __restrict__ b_hh,
                                               const float* __restrict__ hq_cur,
                                               float* __restrict__ hq_next,
                                               const float* __restrict__ enc_out,
                                               float* __restrict__ scores) {
    __shared__ float4 h4[Hsz / 4];
    float* h_lds = (float*)h4;

    int b   = blockIdx.x >> 2;
    int sc  = blockIdx.x & 3;
    int tid = threadIdx.x;

    for (int d = tid; d < Hsz; d += 256) {
        // gbuf accessor: split s, gate g, row j
        #define GB(s_, g_, j_) gbuf[((size_t)(((s_) * 2 + (g_)) * H3 + (j_))) * 64 + b]
        float i_r = GB(0,0,d)       + GB(1,0,d)       + b_ih[d];
        float i_z = GB(0,0,d+Hsz)   + GB(1,0,d+Hsz)   + b_ih[d+Hsz];
        float i_n = GB(0,0,d+2*Hsz) + GB(1,0,d+2*Hsz) + b_ih[d+2*Hsz];
        float h_r = GB(0,1,d)       + GB(1,1,d)       + b_hh[d];
        float h_z = GB(0,1,d+Hsz)   + GB(1,1,d+Hsz)   + b_hh[d+Hsz];
        float h_n = GB(0,1,d+2*Hsz) + GB(1,1,d+2*Hsz) + b_hh[d+2*Hsz];
        #undef GB
        float r = 1.f / (1.f + expf(-(i_r + h_r)));
        float z = 1.f / (1.f + expf(-(i_z + h_z)));
        float n = tanhf(i_n + r * h_n);
        int qa = qaddr(d, b);
        float hp = hq_cur[qa];
        float hn = (1.f - z) * n + z * hp;
        h_lds[d] = hn;
        if (sc == 0) hq_next[qa] = hn;
    }
    __syncthreads();

    int lane = tid & 63;
    int w    = tid >> 6;
    for (int i = 0; i < 32; ++i) {
        int s = sc * 128 + w * 32 + i;
        const float4* e4 = (const float4*)(enc_out + ((size_t)b * Ssz + s) * Hsz);
        float4 ev = e4[lane];
        float4 hv = h4[lane];
        float acc = ev.x*hv.x + ev.y*hv.y + ev.z*hv.z + ev.w*hv.w;
        if (lane < 36) {  // 100 float4 per row: idx 64..99
            float4 ev2 = e4[64 + lane];
            float4 hv2 = h4[64 + lane];
            acc += ev2.x*hv2.x + ev2.y*hv2.y + ev2.z*hv2.z + ev2.w*hv2.w;
        }
        #pragma unroll
        for (int off = 32; off >= 1; off >>= 1) acc += __shfl_xor(acc, off, 64);
        if (lane == 0) scores[b * Ssz + s] = acc;
    }
}

// ---------------------------------------------------------------------------
// Softmax + scatter + argmax + next-x.  grid = 64 blocks (one per b).
// ---------------------------------------------------------------------------
__global__ __launch_bounds__(256) void k_softmax(const float* __restrict__ scores,
                                                 const int* __restrict__ lens,
                                                 const int* __restrict__ uttrs,
                                                 const int* __restrict__ tgt,
                                                 const int* __restrict__ tf_p,
                                                 const float* __restrict__ embedding,
                                                 float* __restrict__ out_probs,
                                                 float* __restrict__ preds_out,
                                                 float* __restrict__ xq,
                                                 int t) {
    __shared__ float sL[Ssz];
    __shared__ float redv[4];
    __shared__ int   redi[4];
    __shared__ float bc_max, bc_sum;
    __shared__ int   bc_idx;

    int b = blockIdx.x;
    int tid = threadIdx.x;
    int lane = tid & 63, w = tid >> 6;
    int len = lens[b];

    for (int s = tid; s < Ssz; s += 256) sL[s] = scores[b * Ssz + s];
    __syncthreads();

    // masked max + argmax (first-index tie-break)
    float bv = -INFINITY; int bi = 0x7fffffff;
    for (int s = tid; s < Ssz; s += 256) {
        if (s < len) {
            float v = sL[s];
            if (v > bv || (v == bv && s < bi)) { bv = v; bi = s; }
        }
    }
    #pragma unroll
    for (int off = 32; off >= 1; off >>= 1) {
        float ov = __shfl_xor(bv, off, 64);
        int   oi = __shfl_xor(bi, off, 64);
        if (ov > bv || (ov == bv && oi < bi)) { bv = ov; bi = oi; }
    }
    if (lane == 0) { redv[w] = bv; redi[w] = bi; }
    __syncthreads();
    if (tid == 0) {
        float mv = redv[0]; int mi = redi[0];
        for (int i = 1; i < 4; ++i)
            if (redv[i] > mv || (redv[i] == mv && redi[i] < mi)) { mv = redv[i]; mi = redi[i]; }
        bc_max = mv; bc_idx = mi;
    }
    __syncthreads();
    float maxv = bc_max;
    int   amax = bc_idx;

    // exp + sum
    float ls = 0.f;
    for (int s = tid; s < Ssz; s += 256) {
        float e = (s < len) ? expf(sL[s] - maxv) : 0.f;
        sL[s] = e;
        ls += e;
    }
    #pragma unroll
    for (int off = 32; off >= 1; off >>= 1) ls += __shfl_xor(ls, off, 64);
    if (lane == 0) redv[w] = ls;
    __syncthreads();
    if (tid == 0) bc_sum = redv[0] + redv[1] + redv[2] + redv[3];
    __syncthreads();
    float sum = bc_sum;

    // scatter probs into vocab bins (masked entries contribute exactly 0 -> skip)
    float* orow = out_probs + (size_t)b * (Lsz * Vsz) + (size_t)t * Vsz;
    for (int s = tid; s < len; s += 256) {
        float p = sL[s] / sum;
        atomicAdd(&orow[uttrs[b * Ssz + s]], p);
    }

    // pred + next input embedding
    int predtok = uttrs[b * Ssz + amax];
    if (tid == 0) preds_out[(size_t)t * Bsz + b] = (float)predtok;
    int nxt = (tf_p[0] != 0) ? tgt[b * Lsz + t] : predtok;
    const float* erow = embedding + (size_t)nxt * Dsz;
    for (int d = tid; d < Dsz; d += 256) {
        xq[qaddr(d, b)] = erow[d];
    }
}

// ---------------------------------------------------------------------------
extern "C" void kernel_launch(void* const* d_in, const int* in_sizes, int n_in,
                              void* d_out, int out_size, void* d_ws, size_t ws_size,
                              hipStream_t stream) {
    const float* enc_hidden = (const float*)d_in[0];   // [1,B,H]
    const float* enc_out    = (const float*)d_in[1];   // [B,S,H]
    const int*   enc_lens   = (const int*)d_in[2];     // [B]
    const int*   uttrs      = (const int*)d_in[3];     // [B,S]
    const int*   tgt        = (const int*)d_in[4];     // [B,L]
    const int*   slot_p     = (const int*)d_in[5];     // scalar
    const int*   tf_p       = (const int*)d_in[6];     // scalar
    const float* embedding  = (const float*)d_in[7];   // [V,D]
    const float* slot_emb   = (const float*)d_in[8];   // [NSLOTS,D]
    const float* W_ih       = (const float*)d_in[9];   // [3H,D]
    const float* W_hh       = (const float*)d_in[10];  // [3H,H]
    const float* b_ih       = (const float*)d_in[11];  // [3H]
    const float* b_hh       = (const float*)d_in[12];  // [3H]

    float* out = (float*)d_out;
    float* ws  = (float*)d_ws;

    // zero the whole output (scatter target is ~99% zeros; preds overwritten)
    hipMemsetAsync(d_out, 0, (size_t)out_size * sizeof(float), stream);

    float* xq     = ws + XQ_OFF;
    float* hqA    = ws + HQA_OFF;
    float* hqB    = ws + HQB_OFF;
    float* gbuf   = ws + GB_OFF;
    float* scores = ws + SC_OFF;

    k_init<<<100, 256, 0, stream>>>(enc_hidden, slot_emb, slot_p, ws);

    float* preds_out = out + (size_t)Bsz * Lsz * Vsz;

    for (int t = 0; t < Lsz; ++t) {
        float* hq_cur  = (t & 1) ? hqB : hqA;
        float* hq_next = (t & 1) ? hqA : hqB;
        k_gates<<<150, 256, 0, stream>>>(W_ih, W_hh, xq, hq_cur, gbuf);
        k_score<<<256, 256, 0, stream>>>(gbuf, b_ih, b_hh, hq_cur, hq_next,
                                         enc_out, scores);
        k_softmax<<<64, 256, 0, stream>>>(scores, enc_lens, uttrs, tgt, tf_p,
                                          embedding, out, preds_out, xq, t);
    }
}